// Round 3
// baseline (28906.625 us; speedup 1.0000x reference)
//
#include <hip/hip_runtime.h>
#include <hip/hip_bf16.h>
#include <cstdint>
#include <cstddef>

#define B_ 8
#define S_ 4096
#define D_ 1024
#define SD_ (S_ * D_)

typedef float v2f __attribute__((ext_vector_type(2)));

// ============================================================================
// Phase 1: z[m][n] = sum_k x[m][k]*W_in[n][k] + b_in[n],  m in [0,32768), n in [0,2048)
//   n <  1024 : gates = sigmoid(z) -> d_out[m*1024 + n]            ([B][S][D] flat)
//   n >= 1024 : p = z              -> ws_p[(s*8 + b)*1024 + n-1024] (time-major,
//               f32 or bf16 per p_bf16 mode)
// 128x128x16 tile, 256 threads, 8x8 microtile (float2-packed FMAs),
// register-prefetch pipeline.
// ============================================================================
__launch_bounds__(256, 2)
__global__ void gemm_in_kernel(const float* __restrict__ x, const float* __restrict__ w,
                               const float* __restrict__ bias, float* __restrict__ outg,
                               void* __restrict__ wsp, int p_bf16)
{
    __shared__ float As[16][132];   // [k][m], +4 pad: 16B-aligned b128 reads, <=2-way banks
    __shared__ float Bs[16][132];   // [k][n]
    const int tid = threadIdx.x;
    const int m0 = blockIdx.y * 128;
    const int n0 = blockIdx.x * 128;
    const int tx = tid & 15;        // n-direction
    const int ty = tid >> 4;        // m-direction
    const int r  = tid >> 2;        // staging row 0..63
    const int kq = tid & 3;         // staging k-quad 0..3

    v2f acc2[8][4];                 // [i][jj2] -> columns jj2*2, jj2*2+1
    #pragma unroll
    for (int i = 0; i < 8; ++i)
        #pragma unroll
        for (int j = 0; j < 4; ++j) acc2[i][j] = (v2f){0.f, 0.f};

    const float* ax = x + (size_t)(m0 + r) * D_ + kq * 4;
    const float* bx = w + (size_t)(n0 + r) * D_ + kq * 4;

    // prologue: prefetch tile 0 into registers
    float4 a0 = *(const float4*)(ax);
    float4 a1 = *(const float4*)(ax + (size_t)64 * D_);
    float4 b0 = *(const float4*)(bx);
    float4 b1 = *(const float4*)(bx + (size_t)64 * D_);

    for (int kt = 0; kt < 64; ++kt) {
        __syncthreads();  // previous iter's compute done before LDS overwrite
        As[kq*4+0][r]    = a0.x; As[kq*4+1][r]    = a0.y; As[kq*4+2][r]    = a0.z; As[kq*4+3][r]    = a0.w;
        As[kq*4+0][r+64] = a1.x; As[kq*4+1][r+64] = a1.y; As[kq*4+2][r+64] = a1.z; As[kq*4+3][r+64] = a1.w;
        Bs[kq*4+0][r]    = b0.x; Bs[kq*4+1][r]    = b0.y; Bs[kq*4+2][r]    = b0.z; Bs[kq*4+3][r]    = b0.w;
        Bs[kq*4+0][r+64] = b1.x; Bs[kq*4+1][r+64] = b1.y; Bs[kq*4+2][r+64] = b1.z; Bs[kq*4+3][r+64] = b1.w;
        __syncthreads();

        // issue next tile's loads NOW; they drain while we compute this tile
        const int k0n = (kt < 63 ? kt + 1 : 63) * 16;
        a0 = *(const float4*)(ax + k0n);
        a1 = *(const float4*)(ax + (size_t)64 * D_ + k0n);
        b0 = *(const float4*)(bx + k0n);
        b1 = *(const float4*)(bx + (size_t)64 * D_ + k0n);

        #pragma unroll
        for (int j = 0; j < 16; ++j) {
            float4 a0v = *(const float4*)&As[j][ty*4];
            float4 a1v = *(const float4*)&As[j][64 + ty*4];
            float4 b0v = *(const float4*)&Bs[j][tx*4];
            float4 b1v = *(const float4*)&Bs[j][64 + tx*4];
            float am[8] = {a0v.x,a0v.y,a0v.z,a0v.w,a1v.x,a1v.y,a1v.z,a1v.w};
            v2f bn2[4];
            bn2[0] = (v2f){b0v.x, b0v.y}; bn2[1] = (v2f){b0v.z, b0v.w};
            bn2[2] = (v2f){b1v.x, b1v.y}; bn2[3] = (v2f){b1v.z, b1v.w};
            #pragma unroll
            for (int i = 0; i < 8; ++i) {
                v2f as = (v2f){am[i], am[i]};
                #pragma unroll
                for (int jj = 0; jj < 4; ++jj)
                    acc2[i][jj] = __builtin_elementwise_fma(as, bn2[jj], acc2[i][jj]);
            }
        }
    }

    const int mloc[2] = {ty * 4, 64 + ty * 4};
    const int nloc[2] = {tx * 4, 64 + tx * 4};
    #pragma unroll
    for (int mh = 0; mh < 2; ++mh) {
        #pragma unroll
        for (int i = 0; i < 4; ++i) {
            const int m  = m0 + mloc[mh] + i;
            const int bb = m >> 12;       // batch
            const int ss = m & 4095;      // timestep
            #pragma unroll
            for (int nh = 0; nh < 2; ++nh) {
                const int nc = n0 + nloc[nh];
                float4 v;
                v.x = acc2[mh*4+i][nh*2+0][0] + bias[nc+0];
                v.y = acc2[mh*4+i][nh*2+0][1] + bias[nc+1];
                v.z = acc2[mh*4+i][nh*2+1][0] + bias[nc+2];
                v.w = acc2[mh*4+i][nh*2+1][1] + bias[nc+3];
                if (nc < D_) {
                    v.x = 1.f / (1.f + __expf(-v.x));
                    v.y = 1.f / (1.f + __expf(-v.y));
                    v.z = 1.f / (1.f + __expf(-v.z));
                    v.w = 1.f / (1.f + __expf(-v.w));
                    *(float4*)(outg + (size_t)m * D_ + nc) = v;            // gates -> d_out
                } else {
                    const size_t off = ((size_t)ss * B_ + bb) * D_ + (nc - D_);
                    if (!p_bf16) {
                        *(float4*)((float*)wsp + off) = v;                 // p f32 -> ws
                    } else {
                        union { __hip_bfloat16 h[4]; uint2 u; } pk;
                        pk.h[0] = __float2bfloat16(v.x); pk.h[1] = __float2bfloat16(v.y);
                        pk.h[2] = __float2bfloat16(v.z); pk.h[3] = __float2bfloat16(v.w);
                        *(uint2*)((__hip_bfloat16*)wsp + off) = pk.u;      // p bf16 -> ws
                    }
                }
            }
        }
    }
}

// ============================================================================
// Phase 2: persistent gated-RNN scan.
// 256 blocks x 256 threads. Group = batch (blockIdx>>5), 32 blocks/group.
// Block owns rows [slice*32, slice*32+32) of W_s, held in VGPRs (128/thread).
// Per step:
//   - hoist g/p loads (HBM latency hides under the flag poll)
//   - barrier-in: lanes 0..31 of wave 0 poll the 32 per-slice flags with ONE
//     wave64 acquire load per iteration (no atomic serialization), then
//     __syncthreads broadcasts readiness to all waves
//   - stage 4KB batch-state -> LDS (relaxed agent atomic loads, LLC-coherent)
//   - matvec (W in VGPRs), shfl + LDS reduce, epilogue on tid<32
//   - publish: tid<32 state stores + tid0 RELEASE flag store, SAME wave
//     (release's vmcnt drain orders all 32 lanes' stores before the flag)
// 3 syncthreads/step. Double-buffered state. Spin bounded + global abort.
// ============================================================================
__launch_bounds__(256, 1)
__global__ void scan_kernel(const float* __restrict__ Ws, const float* __restrict__ bvec,
                            const void* __restrict__ wsp, float* __restrict__ outg,
                            float* __restrict__ state_buf,  // [2][8][1024] f32 (zeroed)
                            unsigned* __restrict__ flags,   // [8][32] @ 128B stride (zeroed)
                            unsigned* __restrict__ abortf,  // zeroed
                            int p_bf16)
{
    const int bid   = blockIdx.x;
    const int batch = bid >> 5;
    const int slice = bid & 31;
    const int tid   = threadIdx.x;
    const int rg    = tid & 3;        // row sub-group (8 rows each)
    const int kg    = tid >> 2;       // k-group 0..63 (16 k's each)
    const int wv    = tid >> 6;       // wave 0..3
    const int lane  = tid & 63;

    __shared__ float sst[64 * 20];    // state, chunk-padded [64 chunks][16+4]
    __shared__ float part[4 * 32];    // cross-wave partials [wave][row]
    __shared__ unsigned sab;

    // --- W_s slice -> registers (one-time) ---
    float wreg[8][16];
    const int k0 = kg * 16;
    #pragma unroll
    for (int rr = 0; rr < 8; ++rr) {
        const float* wp = Ws + (size_t)(slice * 32 + rg * 8 + rr) * D_ + k0;
        float4 w0 = *(const float4*)(wp + 0);
        float4 w1 = *(const float4*)(wp + 4);
        float4 w2 = *(const float4*)(wp + 8);
        float4 w3 = *(const float4*)(wp + 12);
        wreg[rr][0]=w0.x; wreg[rr][1]=w0.y; wreg[rr][2]=w0.z; wreg[rr][3]=w0.w;
        wreg[rr][4]=w1.x; wreg[rr][5]=w1.y; wreg[rr][6]=w1.z; wreg[rr][7]=w1.w;
        wreg[rr][8]=w2.x; wreg[rr][9]=w2.y; wreg[rr][10]=w2.z; wreg[rr][11]=w2.w;
        wreg[rr][12]=w3.x; wreg[rr][13]=w3.y; wreg[rr][14]=w3.z; wreg[rr][15]=w3.w;
    }

    const int grow = slice * 32 + tid;         // epilogue row (valid for tid<32)
    float my_bs = 0.f;
    if (tid < 32) my_bs = bvec[grow];
    if (tid == 0) sab = 0u;
    __syncthreads();                           // sab visible to all

    unsigned* myflag   = &flags[(batch * 32 + slice) * 32];      // 128B-spaced
    unsigned* pollflag = &flags[(batch * 32 + (lane & 31)) * 32];

    for (int t = 0; t < S_; ++t) {
        // ---- hoisted epilogue loads: independent of the barrier ----
        float gv = 0.f, pv = 0.f;
        size_t gidx = 0;
        if (tid < 32) {
            gidx = (size_t)batch * SD_ + (size_t)t * D_ + grow;
            gv = outg[gidx];                                  // gate (read before overwrite)
            const size_t poff = ((size_t)t * B_ + batch) * D_ + grow;
            pv = p_bf16 ? __bfloat162float(((const __hip_bfloat16*)wsp)[poff])
                        : ((const float*)wsp)[poff];
        }

        // ---- barrier-in: wait for all 32 slices to have published s_t ----
        if (t > 0) {
            if (wv == 0) {
                const unsigned target = (unsigned)t;
                int spins = 0;
                while (true) {
                    unsigned v = __hip_atomic_load(pollflag, __ATOMIC_ACQUIRE, __HIP_MEMORY_SCOPE_AGENT);
                    if (__all(v >= target)) break;
                    if ((spins & 63) == 0 &&
                        __hip_atomic_load(abortf, __ATOMIC_RELAXED, __HIP_MEMORY_SCOPE_AGENT) != 0u) {
                        if (lane == 0) sab = 1u;
                        break;
                    }
                    __builtin_amdgcn_s_sleep(1);
                    if (++spins > 3000000) {
                        if (lane == 0) {
                            __hip_atomic_store(abortf, 1u, __ATOMIC_RELAXED, __HIP_MEMORY_SCOPE_AGENT);
                            sab = 1u;
                        }
                        break;
                    }
                }
            }
            __syncthreads();   // (A) readiness + LDS-reuse barrier
            if (sab) return;
        }

        // ---- stage s_t (4KB) -> LDS via 64-bit agent-scope atomic loads ----
        {
            const unsigned long long* src =
                (const unsigned long long*)(state_buf + (((t & 1) * B_) + batch) * D_) + tid * 2;
            unsigned long long u0 = __hip_atomic_load(src + 0, __ATOMIC_RELAXED, __HIP_MEMORY_SCOPE_AGENT);
            unsigned long long u1 = __hip_atomic_load(src + 1, __ATOMIC_RELAXED, __HIP_MEMORY_SCOPE_AGENT);
            float2 s01 = *(float2*)&u0;
            float2 s23 = *(float2*)&u1;
            float4 sv = make_float4(s01.x, s01.y, s23.x, s23.y);
            *(float4*)&sst[(tid >> 2) * 20 + (tid & 3) * 4] = sv;
        }
        __syncthreads();       // (B) state staged

        // ---- matvec partial: 8 rows x 16 k per thread, W in regs, state in LDS ----
        float sreg[16];
        #pragma unroll
        for (int j4 = 0; j4 < 4; ++j4)
            *(float4*)&sreg[j4 * 4] = *(const float4*)&sst[kg * 20 + j4 * 4];

        float acc[8];
        #pragma unroll
        for (int rr = 0; rr < 8; ++rr) acc[rr] = 0.f;
        #pragma unroll
        for (int j = 0; j < 16; ++j)
            #pragma unroll
            for (int rr = 0; rr < 8; ++rr)
                acc[rr] = fmaf(wreg[rr][j], sreg[j], acc[rr]);

        // reduce over kg within wave (lane bits 2..5)
        #pragma unroll
        for (int m = 4; m < 64; m <<= 1)
            #pragma unroll
            for (int rr = 0; rr < 8; ++rr)
                acc[rr] += __shfl_xor(acc[rr], m, 64);

        if ((lane >> 2) == 0) {   // lanes 0..3 hold wave-partials, rg = lane
            #pragma unroll
            for (int rr = 0; rr < 8; ++rr) part[wv * 32 + rg * 8 + rr] = acc[rr];
        }
        __syncthreads();          // (C) partials ready

        // ---- epilogue + publish (tid<32 = wave 0; same-wave flag release) ----
        if (tid < 32) {
            float dot  = part[tid] + part[32 + tid] + part[64 + tid] + part[96 + tid];
            float sold = sst[(grow >> 4) * 20 + (grow & 15)];
            float mix = dot + my_bs + pv;
            float ns  = gv * mix + (1.f - gv) * sold;
            outg[gidx] = ns;                                         // emitted output
            __hip_atomic_store((unsigned*)state_buf + ((((t + 1) & 1) * B_) + batch) * D_ + grow,
                               __float_as_uint(ns), __ATOMIC_RELAXED, __HIP_MEMORY_SCOPE_AGENT);
            if (tid == 0)        // release drains this wave's vmcnt: state stores ordered first
                __hip_atomic_store(myflag, (unsigned)(t + 1), __ATOMIC_RELEASE, __HIP_MEMORY_SCOPE_AGENT);
        }
        // no end barrier: next iteration's (A) protects LDS reuse
    }
}

// ============================================================================
extern "C" void kernel_launch(void* const* d_in, const int* in_sizes, int n_in,
                              void* d_out, int out_size, void* d_ws, size_t ws_size,
                              hipStream_t stream)
{
    const float* x    = (const float*)d_in[0];
    const float* W_in = (const float*)d_in[1];
    const float* b_in = (const float*)d_in[2];
    const float* W_s  = (const float*)d_in[3];
    const float* b_s  = (const float*)d_in[4];
    float* out = (float*)d_out;
    char*  ws  = (char*)d_ws;

    const size_t P_F32   = (size_t)S_ * B_ * D_ * 4;   // 134,217,728
    const size_t P_BF16  = (size_t)S_ * B_ * D_ * 2;   //  67,108,864
    const size_t STATE_B = 2 * B_ * D_ * 4;            //  65,536
    const size_t FLAGS_B = 8 * 32 * 128;               //  32,768
    const size_t TAIL    = STATE_B + FLAGS_B + 256;

    int p_bf16;
    size_t pbytes;
    if (ws_size >= P_F32 + TAIL)       { p_bf16 = 0; pbytes = P_F32; }
    else if (ws_size >= P_BF16 + TAIL) { p_bf16 = 1; pbytes = P_BF16; }
    else return;  // impossible workspace -> loud validation failure

    void*     wsp       = (void*)ws;
    float*    state_buf = (float*)(ws + pbytes);
    unsigned* flags     = (unsigned*)(ws + pbytes + STATE_B);
    unsigned* abortf    = (unsigned*)(ws + pbytes + STATE_B + FLAGS_B);

    // zero state + flags + abort (ws is poisoned 0xAA before every call)
    hipMemsetAsync(ws + pbytes, 0, TAIL, stream);

    dim3 g1(16, 256);
    gemm_in_kernel<<<g1, 256, 0, stream>>>(x, W_in, b_in, out, wsp, p_bf16);
    scan_kernel<<<256, 256, 0, stream>>>(W_s, b_s, wsp, out, state_buf, flags, abortf, p_bf16);
}

// Round 4
// 12291.228 us; speedup vs baseline: 2.3518x; 2.3518x over previous
//
#include <hip/hip_runtime.h>
#include <hip/hip_bf16.h>
#include <cstdint>
#include <cstddef>

#define B_ 8
#define S_ 4096
#define D_ 1024
#define SD_ (S_ * D_)

typedef float v2f __attribute__((ext_vector_type(2)));

// ============================================================================
// Phase 1: z[m][n] = sum_k x[m][k]*W_in[n][k] + b_in[n],  m in [0,32768), n in [0,2048)
//   n <  1024 : gates = sigmoid(z) -> d_out[m*1024 + n]            ([B][S][D] flat)
//   n >= 1024 : p = z              -> ws_p[(s*8 + b)*1024 + n-1024] (time-major,
//               f32 or bf16 per p_bf16 mode)
// 128x128x16 tile, 256 threads, 8x8 microtile (float2-packed FMAs),
// register-prefetch pipeline.  [verified r3: ~1.9 ms]
// ============================================================================
__launch_bounds__(256, 2)
__global__ void gemm_in_kernel(const float* __restrict__ x, const float* __restrict__ w,
                               const float* __restrict__ bias, float* __restrict__ outg,
                               void* __restrict__ wsp, int p_bf16)
{
    __shared__ float As[16][132];   // [k][m], +4 pad: 16B-aligned b128 reads, <=2-way banks
    __shared__ float Bs[16][132];   // [k][n]
    const int tid = threadIdx.x;
    const int m0 = blockIdx.y * 128;
    const int n0 = blockIdx.x * 128;
    const int tx = tid & 15;        // n-direction
    const int ty = tid >> 4;        // m-direction
    const int r  = tid >> 2;        // staging row 0..63
    const int kq = tid & 3;         // staging k-quad 0..3

    v2f acc2[8][4];                 // [i][jj2] -> columns jj2*2, jj2*2+1
    #pragma unroll
    for (int i = 0; i < 8; ++i)
        #pragma unroll
        for (int j = 0; j < 4; ++j) acc2[i][j] = (v2f){0.f, 0.f};

    const float* ax = x + (size_t)(m0 + r) * D_ + kq * 4;
    const float* bx = w + (size_t)(n0 + r) * D_ + kq * 4;

    // prologue: prefetch tile 0 into registers
    float4 a0 = *(const float4*)(ax);
    float4 a1 = *(const float4*)(ax + (size_t)64 * D_);
    float4 b0 = *(const float4*)(bx);
    float4 b1 = *(const float4*)(bx + (size_t)64 * D_);

    for (int kt = 0; kt < 64; ++kt) {
        __syncthreads();  // previous iter's compute done before LDS overwrite
        As[kq*4+0][r]    = a0.x; As[kq*4+1][r]    = a0.y; As[kq*4+2][r]    = a0.z; As[kq*4+3][r]    = a0.w;
        As[kq*4+0][r+64] = a1.x; As[kq*4+1][r+64] = a1.y; As[kq*4+2][r+64] = a1.z; As[kq*4+3][r+64] = a1.w;
        Bs[kq*4+0][r]    = b0.x; Bs[kq*4+1][r]    = b0.y; Bs[kq*4+2][r]    = b0.z; Bs[kq*4+3][r]    = b0.w;
        Bs[kq*4+0][r+64] = b1.x; Bs[kq*4+1][r+64] = b1.y; Bs[kq*4+2][r+64] = b1.z; Bs[kq*4+3][r+64] = b1.w;
        __syncthreads();

        // issue next tile's loads NOW; they drain while we compute this tile
        const int k0n = (kt < 63 ? kt + 1 : 63) * 16;
        a0 = *(const float4*)(ax + k0n);
        a1 = *(const float4*)(ax + (size_t)64 * D_ + k0n);
        b0 = *(const float4*)(bx + k0n);
        b1 = *(const float4*)(bx + (size_t)64 * D_ + k0n);

        #pragma unroll
        for (int j = 0; j < 16; ++j) {
            float4 a0v = *(const float4*)&As[j][ty*4];
            float4 a1v = *(const float4*)&As[j][64 + ty*4];
            float4 b0v = *(const float4*)&Bs[j][tx*4];
            float4 b1v = *(const float4*)&Bs[j][64 + tx*4];
            float am[8] = {a0v.x,a0v.y,a0v.z,a0v.w,a1v.x,a1v.y,a1v.z,a1v.w};
            v2f bn2[4];
            bn2[0] = (v2f){b0v.x, b0v.y}; bn2[1] = (v2f){b0v.z, b0v.w};
            bn2[2] = (v2f){b1v.x, b1v.y}; bn2[3] = (v2f){b1v.z, b1v.w};
            #pragma unroll
            for (int i = 0; i < 8; ++i) {
                v2f as = (v2f){am[i], am[i]};
                #pragma unroll
                for (int jj = 0; jj < 4; ++jj)
                    acc2[i][jj] = __builtin_elementwise_fma(as, bn2[jj], acc2[i][jj]);
            }
        }
    }

    const int mloc[2] = {ty * 4, 64 + ty * 4};
    const int nloc[2] = {tx * 4, 64 + tx * 4};
    #pragma unroll
    for (int mh = 0; mh < 2; ++mh) {
        #pragma unroll
        for (int i = 0; i < 4; ++i) {
            const int m  = m0 + mloc[mh] + i;
            const int bb = m >> 12;       // batch
            const int ss = m & 4095;      // timestep
            #pragma unroll
            for (int nh = 0; nh < 2; ++nh) {
                const int nc = n0 + nloc[nh];
                float4 v;
                v.x = acc2[mh*4+i][nh*2+0][0] + bias[nc+0];
                v.y = acc2[mh*4+i][nh*2+0][1] + bias[nc+1];
                v.z = acc2[mh*4+i][nh*2+1][0] + bias[nc+2];
                v.w = acc2[mh*4+i][nh*2+1][1] + bias[nc+3];
                if (nc < D_) {
                    v.x = 1.f / (1.f + __expf(-v.x));
                    v.y = 1.f / (1.f + __expf(-v.y));
                    v.z = 1.f / (1.f + __expf(-v.z));
                    v.w = 1.f / (1.f + __expf(-v.w));
                    *(float4*)(outg + (size_t)m * D_ + nc) = v;            // gates -> d_out
                } else {
                    const size_t off = ((size_t)ss * B_ + bb) * D_ + (nc - D_);
                    if (!p_bf16) {
                        *(float4*)((float*)wsp + off) = v;                 // p f32 -> ws
                    } else {
                        union { __hip_bfloat16 h[4]; uint2 u; } pk;
                        pk.h[0] = __float2bfloat16(v.x); pk.h[1] = __float2bfloat16(v.y);
                        pk.h[2] = __float2bfloat16(v.z); pk.h[3] = __float2bfloat16(v.w);
                        *(uint2*)((__hip_bfloat16*)wsp + off) = pk.u;      // p bf16 -> ws
                    }
                }
            }
        }
    }
}

// ============================================================================
// Phase 2: persistent gated-RNN scan.
// 256 blocks x 256 threads. Group = batch (blockIdx>>5), 32 blocks/group.
// Block owns rows [slice*32, slice*32+32) of W_s, held in VGPRs (128/thread).
//
// r4 change (from r3 counters: 6.6us/step, FETCH 1.19GB = ~1GB inflation):
//   ALL agent-scope accesses are sc1 (LLC-direct), so acquire/release cache
//   maintenance (buffer_inv per poll iteration, buffer_wbl2 per publish) is
//   pure overhead that was nuking the shared per-XCD L2 continuously.
//   -> poll with RELAXED loads; publish with relaxed stores + explicit
//      s_waitcnt vmcnt(0) + relaxed flag store; outg store moved after flag.
//   __syncthreads() provides the consumer-side ordering (fence + barrier).
// ============================================================================
__launch_bounds__(256, 1)
__global__ void scan_kernel(const float* __restrict__ Ws, const float* __restrict__ bvec,
                            const void* __restrict__ wsp, float* __restrict__ outg,
                            float* __restrict__ state_buf,  // [2][8][1024] f32 (zeroed)
                            unsigned* __restrict__ flags,   // [8][32] @ 128B stride (zeroed)
                            unsigned* __restrict__ abortf,  // zeroed
                            int p_bf16)
{
    const int bid   = blockIdx.x;
    const int batch = bid >> 5;
    const int slice = bid & 31;
    const int tid   = threadIdx.x;
    const int rg    = tid & 3;        // row sub-group (8 rows each)
    const int kg    = tid >> 2;       // k-group 0..63 (16 k's each)
    const int wv    = tid >> 6;       // wave 0..3
    const int lane  = tid & 63;

    __shared__ float sst[64 * 20];    // state, chunk-padded [64 chunks][16+4]
    __shared__ float part[4 * 32];    // cross-wave partials [wave][row]
    __shared__ unsigned sab;

    // --- W_s slice -> registers (one-time) ---
    float wreg[8][16];
    const int k0 = kg * 16;
    #pragma unroll
    for (int rr = 0; rr < 8; ++rr) {
        const float* wp = Ws + (size_t)(slice * 32 + rg * 8 + rr) * D_ + k0;
        float4 w0 = *(const float4*)(wp + 0);
        float4 w1 = *(const float4*)(wp + 4);
        float4 w2 = *(const float4*)(wp + 8);
        float4 w3 = *(const float4*)(wp + 12);
        wreg[rr][0]=w0.x; wreg[rr][1]=w0.y; wreg[rr][2]=w0.z; wreg[rr][3]=w0.w;
        wreg[rr][4]=w1.x; wreg[rr][5]=w1.y; wreg[rr][6]=w1.z; wreg[rr][7]=w1.w;
        wreg[rr][8]=w2.x; wreg[rr][9]=w2.y; wreg[rr][10]=w2.z; wreg[rr][11]=w2.w;
        wreg[rr][12]=w3.x; wreg[rr][13]=w3.y; wreg[rr][14]=w3.z; wreg[rr][15]=w3.w;
    }

    const int grow = slice * 32 + tid;         // epilogue row (valid for tid<32)
    float my_bs = 0.f;
    if (tid < 32) my_bs = bvec[grow];
    if (tid == 0) sab = 0u;
    __syncthreads();                           // sab visible to all

    unsigned* myflag   = &flags[(batch * 32 + slice) * 32];      // 128B-spaced
    unsigned* pollflag = &flags[(batch * 32 + (lane & 31)) * 32];

    for (int t = 0; t < S_; ++t) {
        // ---- hoisted epilogue loads: issue before the poll, drain under it ----
        float gv = 0.f, pv = 0.f;
        size_t gidx = 0;
        if (tid < 32) {
            gidx = (size_t)batch * SD_ + (size_t)t * D_ + grow;
            gv = outg[gidx];                                  // gate (read before overwrite)
            const size_t poff = ((size_t)t * B_ + batch) * D_ + grow;
            pv = p_bf16 ? __bfloat162float(((const __hip_bfloat16*)wsp)[poff])
                        : ((const float*)wsp)[poff];
        }

        // ---- barrier-in: RELAXED poll (sc1 reads LLC directly; no buffer_inv) ----
        if (t > 0) {
            if (wv == 0) {
                const unsigned target = (unsigned)t;
                int spins = 0;
                while (true) {
                    unsigned v = __hip_atomic_load(pollflag, __ATOMIC_RELAXED, __HIP_MEMORY_SCOPE_AGENT);
                    if (__all(v >= target)) break;
                    if ((spins & 63) == 63 &&
                        __hip_atomic_load(abortf, __ATOMIC_RELAXED, __HIP_MEMORY_SCOPE_AGENT) != 0u) {
                        if (lane == 0) sab = 1u;
                        break;
                    }
                    __builtin_amdgcn_s_sleep(1);
                    if (++spins > 1000000) {
                        if (lane == 0) {
                            __hip_atomic_store(abortf, 1u, __ATOMIC_RELAXED, __HIP_MEMORY_SCOPE_AGENT);
                            sab = 1u;
                        }
                        break;
                    }
                }
            }
            __syncthreads();   // (A) readiness broadcast + fence + LDS-reuse barrier
            if (sab) return;
        }

        // ---- stage s_t (4KB) -> LDS via 64-bit relaxed agent loads (LLC-direct) ----
        {
            const unsigned long long* src =
                (const unsigned long long*)(state_buf + (((t & 1) * B_) + batch) * D_) + tid * 2;
            unsigned long long u0 = __hip_atomic_load(src + 0, __ATOMIC_RELAXED, __HIP_MEMORY_SCOPE_AGENT);
            unsigned long long u1 = __hip_atomic_load(src + 1, __ATOMIC_RELAXED, __HIP_MEMORY_SCOPE_AGENT);
            float2 s01 = *(float2*)&u0;
            float2 s23 = *(float2*)&u1;
            float4 sv = make_float4(s01.x, s01.y, s23.x, s23.y);
            *(float4*)&sst[(tid >> 2) * 20 + (tid & 3) * 4] = sv;
        }
        __syncthreads();       // (B) state staged

        // ---- matvec partial: 8 rows x 16 k per thread, W in regs, state in LDS ----
        float sreg[16];
        #pragma unroll
        for (int j4 = 0; j4 < 4; ++j4)
            *(float4*)&sreg[j4 * 4] = *(const float4*)&sst[kg * 20 + j4 * 4];

        float acc[8];
        #pragma unroll
        for (int rr = 0; rr < 8; ++rr) acc[rr] = 0.f;
        #pragma unroll
        for (int j = 0; j < 16; ++j)
            #pragma unroll
            for (int rr = 0; rr < 8; ++rr)
                acc[rr] = fmaf(wreg[rr][j], sreg[j], acc[rr]);

        // reduce over kg within wave (lane bits 2..5)
        #pragma unroll
        for (int m = 4; m < 64; m <<= 1)
            #pragma unroll
            for (int rr = 0; rr < 8; ++rr)
                acc[rr] += __shfl_xor(acc[rr], m, 64);

        if ((lane >> 2) == 0) {   // lanes 0..3 hold wave-partials, rg = lane
            #pragma unroll
            for (int rr = 0; rr < 8; ++rr) part[wv * 32 + rg * 8 + rr] = acc[rr];
        }
        __syncthreads();          // (C) partials ready

        // ---- epilogue + publish (tid<32 = wave 0) ----
        if (tid < 32) {
            float dot  = part[tid] + part[32 + tid] + part[64 + tid] + part[96 + tid];
            float sold = sst[(grow >> 4) * 20 + (grow & 15)];
            float mix = dot + my_bs + pv;
            float ns  = gv * mix + (1.f - gv) * sold;
            // state stores first (critical path to unblock the group)
            __hip_atomic_store((unsigned*)state_buf + ((((t + 1) & 1) * B_) + batch) * D_ + grow,
                               __float_as_uint(ns), __ATOMIC_RELAXED, __HIP_MEMORY_SCOPE_AGENT);
            // order state stores (at LLC) before flag store; wave-wide scalar wait
            asm volatile("s_waitcnt vmcnt(0)" ::: "memory");
            if (tid == 0)
                __hip_atomic_store(myflag, (unsigned)(t + 1), __ATOMIC_RELAXED, __HIP_MEMORY_SCOPE_AGENT);
            // emitted output AFTER the flag: off the group-unblock path
            outg[gidx] = ns;
        }
        // no end barrier: next iteration's (A) protects LDS reuse
    }
}

// ============================================================================
extern "C" void kernel_launch(void* const* d_in, const int* in_sizes, int n_in,
                              void* d_out, int out_size, void* d_ws, size_t ws_size,
                              hipStream_t stream)
{
    const float* x    = (const float*)d_in[0];
    const float* W_in = (const float*)d_in[1];
    const float* b_in = (const float*)d_in[2];
    const float* W_s  = (const float*)d_in[3];
    const float* b_s  = (const float*)d_in[4];
    float* out = (float*)d_out;
    char*  ws  = (char*)d_ws;

    const size_t P_F32   = (size_t)S_ * B_ * D_ * 4;   // 134,217,728
    const size_t P_BF16  = (size_t)S_ * B_ * D_ * 2;   //  67,108,864
    const size_t STATE_B = 2 * B_ * D_ * 4;            //  65,536
    const size_t FLAGS_B = 8 * 32 * 128;               //  32,768
    const size_t TAIL    = STATE_B + FLAGS_B + 256;

    int p_bf16;
    size_t pbytes;
    if (ws_size >= P_F32 + TAIL)       { p_bf16 = 0; pbytes = P_F32; }
    else if (ws_size >= P_BF16 + TAIL) { p_bf16 = 1; pbytes = P_BF16; }
    else return;  // impossible workspace -> loud validation failure

    void*     wsp       = (void*)ws;
    float*    state_buf = (float*)(ws + pbytes);
    unsigned* flags     = (unsigned*)(ws + pbytes + STATE_B);
    unsigned* abortf    = (unsigned*)(ws + pbytes + STATE_B + FLAGS_B);

    // zero state + flags + abort (ws is poisoned 0xAA before every call)
    hipMemsetAsync(ws + pbytes, 0, TAIL, stream);

    dim3 g1(16, 256);
    gemm_in_kernel<<<g1, 256, 0, stream>>>(x, W_in, b_in, out, wsp, p_bf16);
    scan_kernel<<<256, 256, 0, stream>>>(W_s, b_s, wsp, out, state_buf, flags, abortf, p_bf16);
}